// Round 20
// baseline (267.713 us; speedup 1.0000x reference)
//
#include <hip/hip_runtime.h>

// B=4, L=2048, D=1024, H=16, HD=64.
// d_in fp32: x, Wqkv, bqkv, Wproj, bproj. d_out fp32.
// Pipeline: ONE fused fp32->bf16 convert kernel, m97-style bf16 MFMA GEMMs
// with BK=64, LDS-staged tiled epilogue, swapped-operand causal flash
// attention: ONE CHAIN PER WAVE (anti-diagonal pair per block), 4096 waves,
// K/V 1-step ping-pong prefetch (latency off critical path; TLP saturates
// the VALU pipe), lane-major tiled Q2/K2/V2, XCD bh-pin, fixed-reference
// softmax (P = exp2(st)), lsum via ones-MFMA.
//
// Q2/K2 layout (bf16): addr(bh,l,hd) = ((bh*64 + (l>>5))*4 + (hd>>4))*512
//                                      + ((hd>>3)&1)*256 + (l&31)*8 + (hd&7)
// V2 layout (bf16):    addr(bh,l,hd) = ((bh*64 + (l>>5))*4 + (hd>>5)*2
//                                      + ((l>>4)&1))*512 + ((l>>2)&1)*256
//                                      + (hd&31)*8 + ((l&3)|(((l>>3)&1)<<2))

typedef __bf16 bf16x2 __attribute__((ext_vector_type(2)));
typedef __bf16 bf16x4 __attribute__((ext_vector_type(4)));
typedef __bf16 bf16x8 __attribute__((ext_vector_type(8)));
typedef float f32x4 __attribute__((ext_vector_type(4)));
typedef float f32x16 __attribute__((ext_vector_type(16)));
typedef unsigned u32x4 __attribute__((ext_vector_type(4)));

#define MFMA16(a, b, c) __builtin_amdgcn_mfma_f32_16x16x32_bf16(a, b, c, 0, 0, 0)
#define MFMA32(a, b, c) __builtin_amdgcn_mfma_f32_32x32x16_bf16(a, b, c, 0, 0, 0)

__device__ __forceinline__ void gload_lds16(const __bf16* g, __bf16* l) {
    __builtin_amdgcn_global_load_lds(
        (const __attribute__((address_space(1))) void*)g,
        (__attribute__((address_space(3))) void*)l, 16, 0, 0);
}

__device__ __forceinline__ unsigned pkbf(float a, float b) {
    bf16x2 t = {(__bf16)a, (__bf16)b};
    return __builtin_bit_cast(unsigned, t);
}

// ---------------------------------------------------------------------------
// Fused converts: blocks [0,4096) x->xb straight; [4096,7168) wqkv transpose;
// [7168,8192) wproj transpose. 256 threads each.
// ---------------------------------------------------------------------------
__global__ void fused_convert_kernel(const float* __restrict__ x, __bf16* __restrict__ xb,
                                     const float* __restrict__ wqkv, __bf16* __restrict__ wqkvT,
                                     const float* __restrict__ wproj, __bf16* __restrict__ wprojT)
{
    const int blk = blockIdx.x;
    if (blk < 4096) {
        int i = (blk * 256 + threadIdx.x) * 8;
        f32x4 lo = *(const f32x4*)&x[i];
        f32x4 hi = *(const f32x4*)&x[i + 4];
        bf16x8 o;
#pragma unroll
        for (int j = 0; j < 4; ++j) { o[j] = (__bf16)lo[j]; o[j + 4] = (__bf16)hi[j]; }
        *(bf16x8*)&xb[i] = o;
        return;
    }
    __shared__ __bf16 t[32][33];
    const float* in;
    __bf16* out;
    int R, C, bx, by;
    if (blk < 7168) {
        int b2 = blk - 4096;                 // wqkv: grid 96 x 32
        bx = b2 % 96; by = b2 / 96; in = wqkv; out = wqkvT; R = 1024; C = 3072;
    } else {
        int b2 = blk - 7168;                 // wproj: grid 32 x 32
        bx = b2 % 32; by = b2 / 32; in = wproj; out = wprojT; R = 1024; C = 1024;
    }
    const int c0 = bx * 32, r0 = by * 32;
    const int tx = threadIdx.x & 31, ty = threadIdx.x >> 5;
#pragma unroll
    for (int j = 0; j < 4; ++j) {
        int r = ty + j * 8;
        t[tx][r] = (__bf16)in[(size_t)(r0 + r) * C + c0 + tx];
    }
    __syncthreads();
#pragma unroll
    for (int j = 0; j < 4; ++j) {
        int r = ty + j * 8;
        out[(size_t)(c0 + r) * R + r0 + tx] = t[r][tx];
    }
}

// ---------------------------------------------------------------------------
// m97-style GEMM core, BK=64 (16 iters, half the barrier drains).
// ---------------------------------------------------------------------------
#define GEMM_TILE_LOOP(Abase, Bbase)                                               \
    for (int k0 = 0; k0 < 1024; k0 += 64) {                                        \
        __syncthreads();                                                           \
        _Pragma("unroll")                                                          \
        for (int l = 0; l < 4; ++l) {                                              \
            int base = l * 256 + w * 64;                                           \
            int r = (base >> 3) + (lane >> 3);                                     \
            int c = (lane & 7) ^ (r & 7);                                          \
            gload_lds16(&Abase[(size_t)(m0 + r) * 1024 + k0 + c * 8], &As[base * 8]); \
            gload_lds16(&Bbase[(size_t)(n0 + r) * 1024 + k0 + c * 8], &Bs[base * 8]); \
        }                                                                          \
        __syncthreads();                                                           \
        bf16x8 af[2][4], bfr[2][4];                                                \
        _Pragma("unroll")                                                          \
        for (int kk = 0; kk < 2; ++kk) {                                           \
            _Pragma("unroll")                                                      \
            for (int mf = 0; mf < 4; ++mf) {                                       \
                int rr = wr * 64 + mf * 16 + row;                                  \
                af[kk][mf] = *(const bf16x8*)                                      \
                    &As[rr * 64 + (((kk * 4 + g) ^ (rr & 7)) * 8)];                \
            }                                                                      \
            _Pragma("unroll")                                                      \
            for (int nf = 0; nf < 4; ++nf) {                                       \
                int rr = wc * 64 + nf * 16 + row;                                  \
                bfr[kk][nf] = *(const bf16x8*)                                     \
                    &Bs[rr * 64 + (((kk * 4 + g) ^ (rr & 7)) * 8)];                \
            }                                                                      \
        }                                                                          \
        _Pragma("unroll")                                                          \
        for (int kk = 0; kk < 2; ++kk)                                             \
            _Pragma("unroll")                                                      \
            for (int mf = 0; mf < 4; ++mf)                                         \
                _Pragma("unroll")                                                  \
                for (int nf = 0; nf < 4; ++nf)                                     \
                    acc[mf][nf] = MFMA16(af[kk][mf], bfr[kk][nf], acc[mf][nf]);    \
    }

// QKV GEMM. LDS-staged epilogue -> coalesced 1KB chunk stores into Q2/K2/V2.
__global__ __launch_bounds__(256, 2)
void qkv_gemm_kernel(const __bf16* __restrict__ A, const __bf16* __restrict__ Bt,
                     const float* __restrict__ bias,
                     __bf16* __restrict__ q2, __bf16* __restrict__ k2,
                     __bf16* __restrict__ v2)
{
    __shared__ __bf16 stage[16384];           // 32 KB; K-loop: As/Bs 16KB each
    __bf16* const As = stage;                 // 128*64
    __bf16* const Bs = stage + 8192;          // 128*64
    const int tid = threadIdx.x;
    const int lane = tid & 63;
    const int w = tid >> 6;
    const int wr = w >> 1, wc = w & 1;
    const int row = lane & 15, g = lane >> 4;
    const int m0 = blockIdx.x * 128;
    const int n0 = blockIdx.y * 128;

    const f32x4 fzero = {0.f, 0.f, 0.f, 0.f};
    f32x4 acc[4][4];
#pragma unroll
    for (int a = 0; a < 4; ++a)
#pragma unroll
        for (int b = 0; b < 4; ++b) acc[a][b] = fzero;

    GEMM_TILE_LOOP(A, Bt)

    __syncthreads();
    const int part = n0 >> 10;                // 0=q 1=k 2=v (uniform per block)
    const float QSCL = 0.18033688f;           // 0.125 * log2(e)
    if (part == 2) {
#pragma unroll
        for (int mf = 0; mf < 4; ++mf)
#pragma unroll
            for (int nf = 0; nf < 4; ++nf) {
                int nl = nf * 16 + row;
                float bv = bias[n0 + wc * 64 + nl];
                bf16x4 pv;
#pragma unroll
                for (int i = 0; i < 4; ++i)
                    pv[i] = (__bf16)(acc[mf][nf][i] + bv);
                int c = (mf >> 1) * 4 + (nl >> 5) * 2 + (mf & 1);
                int off0 = (g & 1) * 256 + (nl & 31) * 8 + ((g >> 1) & 1) * 4;
                *(unsigned long long*)&stage[w * 4096 + c * 512 + off0] =
                    __builtin_bit_cast(unsigned long long, pv);
            }
    } else {
#pragma unroll
        for (int mf = 0; mf < 4; ++mf)
#pragma unroll
            for (int nf = 0; nf < 4; ++nf) {
                int nl = nf * 16 + row;
                float bv = bias[n0 + wc * 64 + nl];
#pragma unroll
                for (int i = 0; i < 4; ++i) {
                    int ml = mf * 16 + g * 4 + i;
                    float fv = acc[mf][nf][i] + bv;
                    if (part == 0) fv *= QSCL;
                    int c = (ml >> 5) * 4 + (nl >> 4);
                    int off = ((nl >> 3) & 1) * 256 + (ml & 31) * 8 + (nl & 7);
                    stage[w * 4096 + c * 512 + off] = (__bf16)fv;
                }
            }
    }
    {
        const int b = m0 >> 11;
        const int lbase5 = (m0 & 2047) >> 5;
        const int hh = ((n0 & 1023) >> 6) + wc;
        const size_t bh64 = (size_t)(b * 16 + hh) * 64;
        __bf16* dst = part == 0 ? q2 : (part == 1 ? k2 : v2);
#pragma unroll
        for (int c = 0; c < 8; ++c) {
            bf16x8 val = *(const bf16x8*)&stage[w * 4096 + c * 512 + lane * 8];
            size_t gbase = ((bh64 + lbase5 + wr * 2 + (c >> 2)) * 4 + (c & 3)) * 512;
            *(bf16x8*)&dst[gbase + lane * 8] = val;
        }
    }
}

__global__ __launch_bounds__(256, 2)
void proj_gemm_kernel(const __bf16* __restrict__ A, const __bf16* __restrict__ Bt,
                      const float* __restrict__ bias, float* __restrict__ out)
{
    __shared__ __bf16 As[128 * 64];
    __shared__ __bf16 Bs[128 * 64];
    const int tid = threadIdx.x;
    const int lane = tid & 63;
    const int w = tid >> 6;
    const int wr = w >> 1, wc = w & 1;
    const int row = lane & 15, g = lane >> 4;
    const int m0 = blockIdx.x * 128;
    const int n0 = blockIdx.y * 128;

    const f32x4 fzero = {0.f, 0.f, 0.f, 0.f};
    f32x4 acc[4][4];
#pragma unroll
    for (int a = 0; a < 4; ++a)
#pragma unroll
        for (int b = 0; b < 4; ++b) acc[a][b] = fzero;

    GEMM_TILE_LOOP(A, Bt)

#pragma unroll
    for (int mf = 0; mf < 4; ++mf)
#pragma unroll
        for (int nf = 0; nf < 4; ++nf) {
            int n = n0 + wc * 64 + nf * 16 + row;
            float bv = bias[n];
#pragma unroll
            for (int i = 0; i < 4; ++i) {
                int mm = m0 + wr * 64 + mf * 16 + g * 4 + i;
                out[(size_t)mm * 1024 + n] = acc[mf][nf][i] + bv;
            }
        }
}

// ---------------------------------------------------------------------------
// ONE-CHAIN-PER-WAVE swapped-operand causal flash attention (KVBLK=32),
// fixed-reference softmax, lsum via ones-MFMA, K/V 1-step PING-PONG PREFETCH
// (loads issued a full step before use -> L2 latency off critical path).
// Grid 2048 blocks x 128 thr = 4096 waves (4/SIMD). Block i:
// bh = (i&7)*8 + ((i>>3)&7) (XCD pin), pair p = i>>6; wave0 -> q-tile p,
// wave1 -> q-tile 63-p. No LDS/barriers; waves retire independently.
// Prefetch unclamped: overrun lands in adjacent d_ws regions (discarded).
// ---------------------------------------------------------------------------
__global__ __launch_bounds__(128, 4)
void attn_kernel(const __bf16* __restrict__ Q2, const __bf16* __restrict__ K2,
                 const __bf16* __restrict__ V2, __bf16* __restrict__ Yw)
{
    const int tid = threadIdx.x;
    const int lane = tid & 63;
    const int wv = tid >> 6;
    const int col = lane & 31;
    const int hi = lane >> 5;
    const int i0 = blockIdx.x;
    const int bh = (i0 & 7) * 8 + ((i0 >> 3) & 7);
    const int p = i0 >> 6;                     // 0..31
    const int t = wv ? (63 - p) : p;           // this wave's q-tile
    const int qT = t * 32;
    const size_t tb = (size_t)bh * 64;         // tile base

    bf16x8 qf[4];
#pragma unroll
    for (int dc = 0; dc < 4; ++dc)
        qf[dc] = *(const bf16x8*)&Q2[((tb + t) * 4 + dc) * 512 + lane * 8];

    bf16x8 ones;
#pragma unroll
    for (int j = 0; j < 8; ++j) ones[j] = (__bf16)1.0f;

    f32x16 CZ;
#pragma unroll
    for (int i = 0; i < 16; ++i) CZ[i] = 0.f;

    f32x16 Ot[2], Os;
#pragma unroll
    for (int dt = 0; dt < 2; ++dt)
#pragma unroll
        for (int i = 0; i < 16; ++i) Ot[dt][i] = 0.f;
#pragma unroll
    for (int i = 0; i < 16; ++i) Os[i] = 0.f;

    const __bf16* kp = K2 + tb * 2048 + lane * 8;
    const __bf16* vp = V2 + tb * 2048 + lane * 8;

    // preload K(0), V(0)
    bf16x8 kfP[4], vfP[4];
#pragma unroll
    for (int dc = 0; dc < 4; ++dc) {
        kfP[dc] = *(const bf16x8*)&kp[dc * 512];
        vfP[dc] = *(const bf16x8*)&vp[dc * 512];
    }

    for (int kt = 0; kt <= t; ++kt) {
        // prefetch next step's K/V (unclamped; overrun discarded)
        const __bf16* kpn = kp + 2048;
        const __bf16* vpn = vp + 2048;
        bf16x8 kfQ[4], vfQ[4];
#pragma unroll
        for (int dc = 0; dc < 4; ++dc) {
            kfQ[dc] = *(const bf16x8*)&kpn[dc * 512];
            vfQ[dc] = *(const bf16x8*)&vpn[dc * 512];
        }

        f32x16 st;
        __builtin_amdgcn_s_setprio(1);
        st = MFMA32(kfP[0], qf[0], CZ);
        st = MFMA32(kfP[1], qf[1], st);
        st = MFMA32(kfP[2], qf[2], st);
        st = MFMA32(kfP[3], qf[3], st);
        __builtin_amdgcn_s_setprio(0);

        if (kt == t) {
#pragma unroll
            for (int r = 0; r < 16; ++r) {
                int crow = (r & 3) + 8 * (r >> 2) + 4 * hi;
                if (crow > col) st[r] = -1e30f;
            }
        }
#pragma unroll
        for (int r = 0; r < 16; ++r) st[r] = exp2f(st[r]);
        u32x4 w0 = {pkbf(st[0], st[1]), pkbf(st[2], st[3]),
                    pkbf(st[4], st[5]), pkbf(st[6], st[7])};
        u32x4 w1 = {pkbf(st[8], st[9]), pkbf(st[10], st[11]),
                    pkbf(st[12], st[13]), pkbf(st[14], st[15])};
        bf16x8 pa0 = __builtin_bit_cast(bf16x8, w0);
        bf16x8 pa1 = __builtin_bit_cast(bf16x8, w1);

        __builtin_amdgcn_s_setprio(1);
        Os = MFMA32(ones, pa0, Os);
        Os = MFMA32(ones, pa1, Os);
        Ot[0] = MFMA32(vfP[0], pa0, Ot[0]);
        Ot[0] = MFMA32(vfP[1], pa1, Ot[0]);
        Ot[1] = MFMA32(vfP[2], pa0, Ot[1]);
        Ot[1] = MFMA32(vfP[3], pa1, Ot[1]);
        __builtin_amdgcn_s_setprio(0);

#pragma unroll
        for (int dc = 0; dc < 4; ++dc) { kfP[dc] = kfQ[dc]; vfP[dc] = vfQ[dc]; }
        kp = kpn; vp = vpn;
    }

    // ---- epilogue: O^T C-layout col=q(lane-local); l = Os[0] (rows equal)
    const int b = bh >> 4, h = bh & 15;
    const float inv = 1.f / Os[0];
    __bf16* yrow = Yw + ((size_t)(b * 2048 + qT + col)) * 1024 + h * 64;
#pragma unroll
    for (int dt = 0; dt < 2; ++dt)
#pragma unroll
        for (int rg = 0; rg < 4; ++rg) {
            int d0 = dt * 32 + rg * 8 + hi * 4;
            unsigned lo = pkbf(Ot[dt][rg * 4 + 0] * inv, Ot[dt][rg * 4 + 1] * inv);
            unsigned h2 = pkbf(Ot[dt][rg * 4 + 2] * inv, Ot[dt][rg * 4 + 3] * inv);
            *(unsigned long long*)&yrow[d0] =
                (unsigned long long)lo | ((unsigned long long)h2 << 32);
        }
}

// ---------------------------------------------------------------------------
extern "C" void kernel_launch(void* const* d_in, const int* in_sizes, int n_in,
                              void* d_out, int out_size, void* d_ws, size_t ws_size,
                              hipStream_t stream)
{
    const float* x     = (const float*)d_in[0];
    const float* wqkv  = (const float*)d_in[1];
    const float* bqkv  = (const float*)d_in[2];
    const float* wproj = (const float*)d_in[3];
    const float* bproj = (const float*)d_in[4];
    float* out = (float*)d_out;

    const size_t E = (size_t)4 * 16 * 2048 * 64;
    __bf16* q2     = (__bf16*)d_ws;               // E (pre-scaled, tiled)
    __bf16* k2     = q2 + E;                      // E (tiled)
    __bf16* v2     = k2 + E;                      // E (tiled, PV k-placement)
    __bf16* xb     = v2 + E;                      // E
    __bf16* y      = xb;                          // alias
    __bf16* wqkvT  = xb + E;
    __bf16* wprojT = wqkvT + (size_t)3072 * 1024;

    fused_convert_kernel<<<8192, 256, 0, stream>>>(x, xb, wqkv, wqkvT, wproj, wprojT);
    qkv_gemm_kernel<<<dim3(64, 24), 256, 0, stream>>>(xb, wqkvT, bqkv, q2, k2, v2);
    attn_kernel<<<2048, 128, 0, stream>>>(q2, k2, v2, y);
    proj_gemm_kernel<<<dim3(64, 8), 256, 0, stream>>>(y, wprojT, bproj, out);
}

// Round 21
// 154.927 us; speedup vs baseline: 1.7280x; 1.7280x over previous
//
#include <hip/hip_runtime.h>

// B=4, L=2048, D=1024, H=16, HD=64.
// d_in fp32: x, Wqkv, bqkv, Wproj, bproj. d_out fp32.
// Pipeline: ONE fused fp32->bf16 convert kernel, m97-style bf16 MFMA GEMMs
// with BK=64, LDS-staged tiled epilogue, swapped-operand causal flash
// attention: ONE CHAIN PER WAVE (anti-diagonal pair per block), 4096 waves
// (4/SIMD), IN-PLACE K/V prefetch (reload same registers right after last
// use -> latency hidden with zero extra VGPR), lane-major tiled Q2/K2/V2,
// XCD bh-pin, fixed-reference softmax (P = exp2(st)), lsum via ones-MFMA.
//
// Q2/K2 layout (bf16): addr(bh,l,hd) = ((bh*64 + (l>>5))*4 + (hd>>4))*512
//                                      + ((hd>>3)&1)*256 + (l&31)*8 + (hd&7)
// V2 layout (bf16):    addr(bh,l,hd) = ((bh*64 + (l>>5))*4 + (hd>>5)*2
//                                      + ((l>>4)&1))*512 + ((l>>2)&1)*256
//                                      + (hd&31)*8 + ((l&3)|(((l>>3)&1)<<2))

typedef __bf16 bf16x2 __attribute__((ext_vector_type(2)));
typedef __bf16 bf16x4 __attribute__((ext_vector_type(4)));
typedef __bf16 bf16x8 __attribute__((ext_vector_type(8)));
typedef float f32x4 __attribute__((ext_vector_type(4)));
typedef float f32x16 __attribute__((ext_vector_type(16)));
typedef unsigned u32x4 __attribute__((ext_vector_type(4)));

#define MFMA16(a, b, c) __builtin_amdgcn_mfma_f32_16x16x32_bf16(a, b, c, 0, 0, 0)
#define MFMA32(a, b, c) __builtin_amdgcn_mfma_f32_32x32x16_bf16(a, b, c, 0, 0, 0)

__device__ __forceinline__ void gload_lds16(const __bf16* g, __bf16* l) {
    __builtin_amdgcn_global_load_lds(
        (const __attribute__((address_space(1))) void*)g,
        (__attribute__((address_space(3))) void*)l, 16, 0, 0);
}

__device__ __forceinline__ unsigned pkbf(float a, float b) {
    bf16x2 t = {(__bf16)a, (__bf16)b};
    return __builtin_bit_cast(unsigned, t);
}

// ---------------------------------------------------------------------------
// Fused converts: blocks [0,4096) x->xb straight; [4096,7168) wqkv transpose;
// [7168,8192) wproj transpose. 256 threads each.
// ---------------------------------------------------------------------------
__global__ void fused_convert_kernel(const float* __restrict__ x, __bf16* __restrict__ xb,
                                     const float* __restrict__ wqkv, __bf16* __restrict__ wqkvT,
                                     const float* __restrict__ wproj, __bf16* __restrict__ wprojT)
{
    const int blk = blockIdx.x;
    if (blk < 4096) {
        int i = (blk * 256 + threadIdx.x) * 8;
        f32x4 lo = *(const f32x4*)&x[i];
        f32x4 hi = *(const f32x4*)&x[i + 4];
        bf16x8 o;
#pragma unroll
        for (int j = 0; j < 4; ++j) { o[j] = (__bf16)lo[j]; o[j + 4] = (__bf16)hi[j]; }
        *(bf16x8*)&xb[i] = o;
        return;
    }
    __shared__ __bf16 t[32][33];
    const float* in;
    __bf16* out;
    int R, C, bx, by;
    if (blk < 7168) {
        int b2 = blk - 4096;                 // wqkv: grid 96 x 32
        bx = b2 % 96; by = b2 / 96; in = wqkv; out = wqkvT; R = 1024; C = 3072;
    } else {
        int b2 = blk - 7168;                 // wproj: grid 32 x 32
        bx = b2 % 32; by = b2 / 32; in = wproj; out = wprojT; R = 1024; C = 1024;
    }
    const int c0 = bx * 32, r0 = by * 32;
    const int tx = threadIdx.x & 31, ty = threadIdx.x >> 5;
#pragma unroll
    for (int j = 0; j < 4; ++j) {
        int r = ty + j * 8;
        t[tx][r] = (__bf16)in[(size_t)(r0 + r) * C + c0 + tx];
    }
    __syncthreads();
#pragma unroll
    for (int j = 0; j < 4; ++j) {
        int r = ty + j * 8;
        out[(size_t)(c0 + r) * R + r0 + tx] = t[r][tx];
    }
}

// ---------------------------------------------------------------------------
// m97-style GEMM core, BK=64 (16 iters, half the barrier drains).
// ---------------------------------------------------------------------------
#define GEMM_TILE_LOOP(Abase, Bbase)                                               \
    for (int k0 = 0; k0 < 1024; k0 += 64) {                                        \
        __syncthreads();                                                           \
        _Pragma("unroll")                                                          \
        for (int l = 0; l < 4; ++l) {                                              \
            int base = l * 256 + w * 64;                                           \
            int r = (base >> 3) + (lane >> 3);                                     \
            int c = (lane & 7) ^ (r & 7);                                          \
            gload_lds16(&Abase[(size_t)(m0 + r) * 1024 + k0 + c * 8], &As[base * 8]); \
            gload_lds16(&Bbase[(size_t)(n0 + r) * 1024 + k0 + c * 8], &Bs[base * 8]); \
        }                                                                          \
        __syncthreads();                                                           \
        bf16x8 af[2][4], bfr[2][4];                                                \
        _Pragma("unroll")                                                          \
        for (int kk = 0; kk < 2; ++kk) {                                           \
            _Pragma("unroll")                                                      \
            for (int mf = 0; mf < 4; ++mf) {                                       \
                int rr = wr * 64 + mf * 16 + row;                                  \
                af[kk][mf] = *(const bf16x8*)                                      \
                    &As[rr * 64 + (((kk * 4 + g) ^ (rr & 7)) * 8)];                \
            }                                                                      \
            _Pragma("unroll")                                                      \
            for (int nf = 0; nf < 4; ++nf) {                                       \
                int rr = wc * 64 + nf * 16 + row;                                  \
                bfr[kk][nf] = *(const bf16x8*)                                     \
                    &Bs[rr * 64 + (((kk * 4 + g) ^ (rr & 7)) * 8)];                \
            }                                                                      \
        }                                                                          \
        _Pragma("unroll")                                                          \
        for (int kk = 0; kk < 2; ++kk)                                             \
            _Pragma("unroll")                                                      \
            for (int mf = 0; mf < 4; ++mf)                                         \
                _Pragma("unroll")                                                  \
                for (int nf = 0; nf < 4; ++nf)                                     \
                    acc[mf][nf] = MFMA16(af[kk][mf], bfr[kk][nf], acc[mf][nf]);    \
    }

// QKV GEMM. LDS-staged epilogue -> coalesced 1KB chunk stores into Q2/K2/V2.
__global__ __launch_bounds__(256, 2)
void qkv_gemm_kernel(const __bf16* __restrict__ A, const __bf16* __restrict__ Bt,
                     const float* __restrict__ bias,
                     __bf16* __restrict__ q2, __bf16* __restrict__ k2,
                     __bf16* __restrict__ v2)
{
    __shared__ __bf16 stage[16384];           // 32 KB; K-loop: As/Bs 16KB each
    __bf16* const As = stage;                 // 128*64
    __bf16* const Bs = stage + 8192;          // 128*64
    const int tid = threadIdx.x;
    const int lane = tid & 63;
    const int w = tid >> 6;
    const int wr = w >> 1, wc = w & 1;
    const int row = lane & 15, g = lane >> 4;
    const int m0 = blockIdx.x * 128;
    const int n0 = blockIdx.y * 128;

    const f32x4 fzero = {0.f, 0.f, 0.f, 0.f};
    f32x4 acc[4][4];
#pragma unroll
    for (int a = 0; a < 4; ++a)
#pragma unroll
        for (int b = 0; b < 4; ++b) acc[a][b] = fzero;

    GEMM_TILE_LOOP(A, Bt)

    __syncthreads();
    const int part = n0 >> 10;                // 0=q 1=k 2=v (uniform per block)
    const float QSCL = 0.18033688f;           // 0.125 * log2(e)
    if (part == 2) {
#pragma unroll
        for (int mf = 0; mf < 4; ++mf)
#pragma unroll
            for (int nf = 0; nf < 4; ++nf) {
                int nl = nf * 16 + row;
                float bv = bias[n0 + wc * 64 + nl];
                bf16x4 pv;
#pragma unroll
                for (int i = 0; i < 4; ++i)
                    pv[i] = (__bf16)(acc[mf][nf][i] + bv);
                int c = (mf >> 1) * 4 + (nl >> 5) * 2 + (mf & 1);
                int off0 = (g & 1) * 256 + (nl & 31) * 8 + ((g >> 1) & 1) * 4;
                *(unsigned long long*)&stage[w * 4096 + c * 512 + off0] =
                    __builtin_bit_cast(unsigned long long, pv);
            }
    } else {
#pragma unroll
        for (int mf = 0; mf < 4; ++mf)
#pragma unroll
            for (int nf = 0; nf < 4; ++nf) {
                int nl = nf * 16 + row;
                float bv = bias[n0 + wc * 64 + nl];
#pragma unroll
                for (int i = 0; i < 4; ++i) {
                    int ml = mf * 16 + g * 4 + i;
                    float fv = acc[mf][nf][i] + bv;
                    if (part == 0) fv *= QSCL;
                    int c = (ml >> 5) * 4 + (nl >> 4);
                    int off = ((nl >> 3) & 1) * 256 + (ml & 31) * 8 + (nl & 7);
                    stage[w * 4096 + c * 512 + off] = (__bf16)fv;
                }
            }
    }
    {
        const int b = m0 >> 11;
        const int lbase5 = (m0 & 2047) >> 5;
        const int hh = ((n0 & 1023) >> 6) + wc;
        const size_t bh64 = (size_t)(b * 16 + hh) * 64;
        __bf16* dst = part == 0 ? q2 : (part == 1 ? k2 : v2);
#pragma unroll
        for (int c = 0; c < 8; ++c) {
            bf16x8 val = *(const bf16x8*)&stage[w * 4096 + c * 512 + lane * 8];
            size_t gbase = ((bh64 + lbase5 + wr * 2 + (c >> 2)) * 4 + (c & 3)) * 512;
            *(bf16x8*)&dst[gbase + lane * 8] = val;
        }
    }
}

__global__ __launch_bounds__(256, 2)
void proj_gemm_kernel(const __bf16* __restrict__ A, const __bf16* __restrict__ Bt,
                      const float* __restrict__ bias, float* __restrict__ out)
{
    __shared__ __bf16 As[128 * 64];
    __shared__ __bf16 Bs[128 * 64];
    const int tid = threadIdx.x;
    const int lane = tid & 63;
    const int w = tid >> 6;
    const int wr = w >> 1, wc = w & 1;
    const int row = lane & 15, g = lane >> 4;
    const int m0 = blockIdx.x * 128;
    const int n0 = blockIdx.y * 128;

    const f32x4 fzero = {0.f, 0.f, 0.f, 0.f};
    f32x4 acc[4][4];
#pragma unroll
    for (int a = 0; a < 4; ++a)
#pragma unroll
        for (int b = 0; b < 4; ++b) acc[a][b] = fzero;

    GEMM_TILE_LOOP(A, Bt)

#pragma unroll
    for (int mf = 0; mf < 4; ++mf)
#pragma unroll
        for (int nf = 0; nf < 4; ++nf) {
            int n = n0 + wc * 64 + nf * 16 + row;
            float bv = bias[n];
#pragma unroll
            for (int i = 0; i < 4; ++i) {
                int mm = m0 + wr * 64 + mf * 16 + g * 4 + i;
                out[(size_t)mm * 1024 + n] = acc[mf][nf][i] + bv;
            }
        }
}

// ---------------------------------------------------------------------------
// ONE-CHAIN-PER-WAVE swapped-operand causal flash attention (KVBLK=32),
// fixed-reference softmax, lsum via ones-MFMA, IN-PLACE K/V prefetch:
// kfP reloaded (same registers) right after QK^T consumes it (covered by
// softmax+PV, ~350cy); vfP reloaded right after PV (covered by next QK^T
// +softmax). Zero extra VGPR vs JIT. Grid 2048 x 128 thr = 4096 waves
// (4/SIMD). bh = (i&7)*8+((i>>3)&7) XCD pin; wave0 -> q-tile p, wave1 ->
// 63-p. No LDS/barriers. Prefetch overrun lands in adjacent d_ws regions.
// ---------------------------------------------------------------------------
__global__ __launch_bounds__(128, 4)
void attn_kernel(const __bf16* __restrict__ Q2, const __bf16* __restrict__ K2,
                 const __bf16* __restrict__ V2, __bf16* __restrict__ Yw)
{
    const int tid = threadIdx.x;
    const int lane = tid & 63;
    const int wv = tid >> 6;
    const int col = lane & 31;
    const int hi = lane >> 5;
    const int i0 = blockIdx.x;
    const int bh = (i0 & 7) * 8 + ((i0 >> 3) & 7);
    const int p = i0 >> 6;                     // 0..31
    const int t = wv ? (63 - p) : p;           // this wave's q-tile
    const int qT = t * 32;
    const size_t tb = (size_t)bh * 64;         // tile base

    bf16x8 qf[4];
#pragma unroll
    for (int dc = 0; dc < 4; ++dc)
        qf[dc] = *(const bf16x8*)&Q2[((tb + t) * 4 + dc) * 512 + lane * 8];

    bf16x8 ones;
#pragma unroll
    for (int j = 0; j < 8; ++j) ones[j] = (__bf16)1.0f;

    f32x16 CZ;
#pragma unroll
    for (int i = 0; i < 16; ++i) CZ[i] = 0.f;

    f32x16 Ot[2], Os;
#pragma unroll
    for (int dt = 0; dt < 2; ++dt)
#pragma unroll
        for (int i = 0; i < 16; ++i) Ot[dt][i] = 0.f;
#pragma unroll
    for (int i = 0; i < 16; ++i) Os[i] = 0.f;

    const __bf16* kp = K2 + tb * 2048 + lane * 8;
    const __bf16* vp = V2 + tb * 2048 + lane * 8;

    // preload K(0), V(0)
    bf16x8 kfP[4], vfP[4];
#pragma unroll
    for (int dc = 0; dc < 4; ++dc) {
        kfP[dc] = *(const bf16x8*)&kp[dc * 512];
        vfP[dc] = *(const bf16x8*)&vp[dc * 512];
    }

    for (int kt = 0; kt <= t; ++kt) {
        f32x16 st;
        __builtin_amdgcn_s_setprio(1);
        st = MFMA32(kfP[0], qf[0], CZ);
        st = MFMA32(kfP[1], qf[1], st);
        st = MFMA32(kfP[2], qf[2], st);
        st = MFMA32(kfP[3], qf[3], st);
        __builtin_amdgcn_s_setprio(0);

        // in-place K prefetch: kfP dead after QK^T issue; reload same regs.
        // Latency covered by softmax + PV below. (Unclamped; overrun ok.)
        kp += 2048;
#pragma unroll
        for (int dc = 0; dc < 4; ++dc)
            kfP[dc] = *(const bf16x8*)&kp[dc * 512];

        if (kt == t) {
#pragma unroll
            for (int r = 0; r < 16; ++r) {
                int crow = (r & 3) + 8 * (r >> 2) + 4 * hi;
                if (crow > col) st[r] = -1e30f;
            }
        }
#pragma unroll
        for (int r = 0; r < 16; ++r) st[r] = exp2f(st[r]);
        u32x4 w0 = {pkbf(st[0], st[1]), pkbf(st[2], st[3]),
                    pkbf(st[4], st[5]), pkbf(st[6], st[7])};
        u32x4 w1 = {pkbf(st[8], st[9]), pkbf(st[10], st[11]),
                    pkbf(st[12], st[13]), pkbf(st[14], st[15])};
        bf16x8 pa0 = __builtin_bit_cast(bf16x8, w0);
        bf16x8 pa1 = __builtin_bit_cast(bf16x8, w1);

        __builtin_amdgcn_s_setprio(1);
        Os = MFMA32(ones, pa0, Os);
        Os = MFMA32(ones, pa1, Os);
        Ot[0] = MFMA32(vfP[0], pa0, Ot[0]);
        Ot[0] = MFMA32(vfP[1], pa1, Ot[0]);
        Ot[1] = MFMA32(vfP[2], pa0, Ot[1]);
        Ot[1] = MFMA32(vfP[3], pa1, Ot[1]);
        __builtin_amdgcn_s_setprio(0);

        // in-place V prefetch: vfP dead after PV issue; reload same regs.
        // Latency covered by next step's QK^T + softmax.
        vp += 2048;
#pragma unroll
        for (int dc = 0; dc < 4; ++dc)
            vfP[dc] = *(const bf16x8*)&vp[dc * 512];
    }

    // ---- epilogue: O^T C-layout col=q(lane-local); l = Os[0] (rows equal)
    const int b = bh >> 4, h = bh & 15;
    const float inv = 1.f / Os[0];
    __bf16* yrow = Yw + ((size_t)(b * 2048 + qT + col)) * 1024 + h * 64;
#pragma unroll
    for (int dt = 0; dt < 2; ++dt)
#pragma unroll
        for (int rg = 0; rg < 4; ++rg) {
            int d0 = dt * 32 + rg * 8 + hi * 4;
            unsigned lo = pkbf(Ot[dt][rg * 4 + 0] * inv, Ot[dt][rg * 4 + 1] * inv);
            unsigned h2 = pkbf(Ot[dt][rg * 4 + 2] * inv, Ot[dt][rg * 4 + 3] * inv);
            *(unsigned long long*)&yrow[d0] =
                (unsigned long long)lo | ((unsigned long long)h2 << 32);
        }
}

// ---------------------------------------------------------------------------
extern "C" void kernel_launch(void* const* d_in, const int* in_sizes, int n_in,
                              void* d_out, int out_size, void* d_ws, size_t ws_size,
                              hipStream_t stream)
{
    const float* x     = (const float*)d_in[0];
    const float* wqkv  = (const float*)d_in[1];
    const float* bqkv  = (const float*)d_in[2];
    const float* wproj = (const float*)d_in[3];
    const float* bproj = (const float*)d_in[4];
    float* out = (float*)d_out;

    const size_t E = (size_t)4 * 16 * 2048 * 64;
    __bf16* q2     = (__bf16*)d_ws;               // E (pre-scaled, tiled)
    __bf16* k2     = q2 + E;                      // E (tiled)
    __bf16* v2     = k2 + E;                      // E (tiled, PV k-placement)
    __bf16* xb     = v2 + E;                      // E
    __bf16* y      = xb;                          // alias
    __bf16* wqkvT  = xb + E;
    __bf16* wprojT = wqkvT + (size_t)3072 * 1024;

    fused_convert_kernel<<<8192, 256, 0, stream>>>(x, xb, wqkv, wqkvT, wproj, wprojT);
    qkv_gemm_kernel<<<dim3(64, 24), 256, 0, stream>>>(xb, wqkvT, bqkv, q2, k2, v2);
    attn_kernel<<<2048, 128, 0, stream>>>(q2, k2, v2, y);
    proj_gemm_kernel<<<dim3(64, 8), 256, 0, stream>>>(y, wprojT, bproj, out);
}

// Round 22
// 151.881 us; speedup vs baseline: 1.7626x; 1.0201x over previous
//
#include <hip/hip_runtime.h>

// B=4, L=2048, D=1024, H=16, HD=64.
// d_in fp32: x, Wqkv, bqkv, Wproj, bproj. d_out fp32.
// Pipeline: ONE fused fp32->bf16 convert kernel, m97-style bf16 MFMA GEMMs
// with BK=64, LDS-staged tiled epilogue, swapped-operand causal flash
// attention: DUAL-CHAIN pair-balanced waves (R18 structure, shared K/V
// loads) with IN-PLACE K/V prefetch (reload same regs after last use; no
// ping-pong copies), lane-major tiled Q2/K2/V2, XCD bh-pin, fixed-reference
// softmax (P = exp2(st)), lsum via ones-MFMA.
//
// Q2/K2 layout (bf16): addr(bh,l,hd) = ((bh*64 + (l>>5))*4 + (hd>>4))*512
//                                      + ((hd>>3)&1)*256 + (l&31)*8 + (hd&7)
// V2 layout (bf16):    addr(bh,l,hd) = ((bh*64 + (l>>5))*4 + (hd>>5)*2
//                                      + ((l>>4)&1))*512 + ((l>>2)&1)*256
//                                      + (hd&31)*8 + ((l&3)|(((l>>3)&1)<<2))

typedef __bf16 bf16x2 __attribute__((ext_vector_type(2)));
typedef __bf16 bf16x4 __attribute__((ext_vector_type(4)));
typedef __bf16 bf16x8 __attribute__((ext_vector_type(8)));
typedef float f32x4 __attribute__((ext_vector_type(4)));
typedef float f32x16 __attribute__((ext_vector_type(16)));
typedef unsigned u32x4 __attribute__((ext_vector_type(4)));

#define MFMA16(a, b, c) __builtin_amdgcn_mfma_f32_16x16x32_bf16(a, b, c, 0, 0, 0)
#define MFMA32(a, b, c) __builtin_amdgcn_mfma_f32_32x32x16_bf16(a, b, c, 0, 0, 0)

__device__ __forceinline__ void gload_lds16(const __bf16* g, __bf16* l) {
    __builtin_amdgcn_global_load_lds(
        (const __attribute__((address_space(1))) void*)g,
        (__attribute__((address_space(3))) void*)l, 16, 0, 0);
}

__device__ __forceinline__ unsigned pkbf(float a, float b) {
    bf16x2 t = {(__bf16)a, (__bf16)b};
    return __builtin_bit_cast(unsigned, t);
}

// ---------------------------------------------------------------------------
// Fused converts: blocks [0,4096) x->xb straight; [4096,7168) wqkv transpose;
// [7168,8192) wproj transpose. 256 threads each.
// ---------------------------------------------------------------------------
__global__ void fused_convert_kernel(const float* __restrict__ x, __bf16* __restrict__ xb,
                                     const float* __restrict__ wqkv, __bf16* __restrict__ wqkvT,
                                     const float* __restrict__ wproj, __bf16* __restrict__ wprojT)
{
    const int blk = blockIdx.x;
    if (blk < 4096) {
        int i = (blk * 256 + threadIdx.x) * 8;
        f32x4 lo = *(const f32x4*)&x[i];
        f32x4 hi = *(const f32x4*)&x[i + 4];
        bf16x8 o;
#pragma unroll
        for (int j = 0; j < 4; ++j) { o[j] = (__bf16)lo[j]; o[j + 4] = (__bf16)hi[j]; }
        *(bf16x8*)&xb[i] = o;
        return;
    }
    __shared__ __bf16 t[32][33];
    const float* in;
    __bf16* out;
    int R, C, bx, by;
    if (blk < 7168) {
        int b2 = blk - 4096;                 // wqkv: grid 96 x 32
        bx = b2 % 96; by = b2 / 96; in = wqkv; out = wqkvT; R = 1024; C = 3072;
    } else {
        int b2 = blk - 7168;                 // wproj: grid 32 x 32
        bx = b2 % 32; by = b2 / 32; in = wproj; out = wprojT; R = 1024; C = 1024;
    }
    const int c0 = bx * 32, r0 = by * 32;
    const int tx = threadIdx.x & 31, ty = threadIdx.x >> 5;
#pragma unroll
    for (int j = 0; j < 4; ++j) {
        int r = ty + j * 8;
        t[tx][r] = (__bf16)in[(size_t)(r0 + r) * C + c0 + tx];
    }
    __syncthreads();
#pragma unroll
    for (int j = 0; j < 4; ++j) {
        int r = ty + j * 8;
        out[(size_t)(c0 + r) * R + r0 + tx] = t[r][tx];
    }
}

// ---------------------------------------------------------------------------
// m97-style GEMM core, BK=64 (16 iters, half the barrier drains).
// ---------------------------------------------------------------------------
#define GEMM_TILE_LOOP(Abase, Bbase)                                               \
    for (int k0 = 0; k0 < 1024; k0 += 64) {                                        \
        __syncthreads();                                                           \
        _Pragma("unroll")                                                          \
        for (int l = 0; l < 4; ++l) {                                              \
            int base = l * 256 + w * 64;                                           \
            int r = (base >> 3) + (lane >> 3);                                     \
            int c = (lane & 7) ^ (r & 7);                                          \
            gload_lds16(&Abase[(size_t)(m0 + r) * 1024 + k0 + c * 8], &As[base * 8]); \
            gload_lds16(&Bbase[(size_t)(n0 + r) * 1024 + k0 + c * 8], &Bs[base * 8]); \
        }                                                                          \
        __syncthreads();                                                           \
        bf16x8 af[2][4], bfr[2][4];                                                \
        _Pragma("unroll")                                                          \
        for (int kk = 0; kk < 2; ++kk) {                                           \
            _Pragma("unroll")                                                      \
            for (int mf = 0; mf < 4; ++mf) {                                       \
                int rr = wr * 64 + mf * 16 + row;                                  \
                af[kk][mf] = *(const bf16x8*)                                      \
                    &As[rr * 64 + (((kk * 4 + g) ^ (rr & 7)) * 8)];                \
            }                                                                      \
            _Pragma("unroll")                                                      \
            for (int nf = 0; nf < 4; ++nf) {                                       \
                int rr = wc * 64 + nf * 16 + row;                                  \
                bfr[kk][nf] = *(const bf16x8*)                                     \
                    &Bs[rr * 64 + (((kk * 4 + g) ^ (rr & 7)) * 8)];                \
            }                                                                      \
        }                                                                          \
        _Pragma("unroll")                                                          \
        for (int kk = 0; kk < 2; ++kk)                                             \
            _Pragma("unroll")                                                      \
            for (int mf = 0; mf < 4; ++mf)                                         \
                _Pragma("unroll")                                                  \
                for (int nf = 0; nf < 4; ++nf)                                     \
                    acc[mf][nf] = MFMA16(af[kk][mf], bfr[kk][nf], acc[mf][nf]);    \
    }

// QKV GEMM. LDS-staged epilogue -> coalesced 1KB chunk stores into Q2/K2/V2.
__global__ __launch_bounds__(256, 2)
void qkv_gemm_kernel(const __bf16* __restrict__ A, const __bf16* __restrict__ Bt,
                     const float* __restrict__ bias,
                     __bf16* __restrict__ q2, __bf16* __restrict__ k2,
                     __bf16* __restrict__ v2)
{
    __shared__ __bf16 stage[16384];           // 32 KB; K-loop: As/Bs 16KB each
    __bf16* const As = stage;                 // 128*64
    __bf16* const Bs = stage + 8192;          // 128*64
    const int tid = threadIdx.x;
    const int lane = tid & 63;
    const int w = tid >> 6;
    const int wr = w >> 1, wc = w & 1;
    const int row = lane & 15, g = lane >> 4;
    const int m0 = blockIdx.x * 128;
    const int n0 = blockIdx.y * 128;

    const f32x4 fzero = {0.f, 0.f, 0.f, 0.f};
    f32x4 acc[4][4];
#pragma unroll
    for (int a = 0; a < 4; ++a)
#pragma unroll
        for (int b = 0; b < 4; ++b) acc[a][b] = fzero;

    GEMM_TILE_LOOP(A, Bt)

    __syncthreads();
    const int part = n0 >> 10;                // 0=q 1=k 2=v (uniform per block)
    const float QSCL = 0.18033688f;           // 0.125 * log2(e)
    if (part == 2) {
#pragma unroll
        for (int mf = 0; mf < 4; ++mf)
#pragma unroll
            for (int nf = 0; nf < 4; ++nf) {
                int nl = nf * 16 + row;
                float bv = bias[n0 + wc * 64 + nl];
                bf16x4 pv;
#pragma unroll
                for (int i = 0; i < 4; ++i)
                    pv[i] = (__bf16)(acc[mf][nf][i] + bv);
                int c = (mf >> 1) * 4 + (nl >> 5) * 2 + (mf & 1);
                int off0 = (g & 1) * 256 + (nl & 31) * 8 + ((g >> 1) & 1) * 4;
                *(unsigned long long*)&stage[w * 4096 + c * 512 + off0] =
                    __builtin_bit_cast(unsigned long long, pv);
            }
    } else {
#pragma unroll
        for (int mf = 0; mf < 4; ++mf)
#pragma unroll
            for (int nf = 0; nf < 4; ++nf) {
                int nl = nf * 16 + row;
                float bv = bias[n0 + wc * 64 + nl];
#pragma unroll
                for (int i = 0; i < 4; ++i) {
                    int ml = mf * 16 + g * 4 + i;
                    float fv = acc[mf][nf][i] + bv;
                    if (part == 0) fv *= QSCL;
                    int c = (ml >> 5) * 4 + (nl >> 4);
                    int off = ((nl >> 3) & 1) * 256 + (ml & 31) * 8 + (nl & 7);
                    stage[w * 4096 + c * 512 + off] = (__bf16)fv;
                }
            }
    }
    {
        const int b = m0 >> 11;
        const int lbase5 = (m0 & 2047) >> 5;
        const int hh = ((n0 & 1023) >> 6) + wc;
        const size_t bh64 = (size_t)(b * 16 + hh) * 64;
        __bf16* dst = part == 0 ? q2 : (part == 1 ? k2 : v2);
#pragma unroll
        for (int c = 0; c < 8; ++c) {
            bf16x8 val = *(const bf16x8*)&stage[w * 4096 + c * 512 + lane * 8];
            size_t gbase = ((bh64 + lbase5 + wr * 2 + (c >> 2)) * 4 + (c & 3)) * 512;
            *(bf16x8*)&dst[gbase + lane * 8] = val;
        }
    }
}

__global__ __launch_bounds__(256, 2)
void proj_gemm_kernel(const __bf16* __restrict__ A, const __bf16* __restrict__ Bt,
                      const float* __restrict__ bias, float* __restrict__ out)
{
    __shared__ __bf16 As[128 * 64];
    __shared__ __bf16 Bs[128 * 64];
    const int tid = threadIdx.x;
    const int lane = tid & 63;
    const int w = tid >> 6;
    const int wr = w >> 1, wc = w & 1;
    const int row = lane & 15, g = lane >> 4;
    const int m0 = blockIdx.x * 128;
    const int n0 = blockIdx.y * 128;

    const f32x4 fzero = {0.f, 0.f, 0.f, 0.f};
    f32x4 acc[4][4];
#pragma unroll
    for (int a = 0; a < 4; ++a)
#pragma unroll
        for (int b = 0; b < 4; ++b) acc[a][b] = fzero;

    GEMM_TILE_LOOP(A, Bt)

#pragma unroll
    for (int mf = 0; mf < 4; ++mf)
#pragma unroll
        for (int nf = 0; nf < 4; ++nf) {
            int n = n0 + wc * 64 + nf * 16 + row;
            float bv = bias[n];
#pragma unroll
            for (int i = 0; i < 4; ++i) {
                int mm = m0 + wr * 64 + mf * 16 + g * 4 + i;
                out[(size_t)mm * 1024 + n] = acc[mf][nf][i] + bv;
            }
        }
}

// ---------------------------------------------------------------------------
// DUAL-CHAIN pair-balanced swapped-operand causal flash attention (KVBLK=32)
// with fixed-reference softmax and IN-PLACE K/V prefetch:
// kfP reloaded (same regs) right after both chains' QK^T consume it
// (covered by 2x softmax + PV, ~500cy); vfP reloaded right after PV
// (covered by next step's QK^T + softmax). K/V loads shared across chains.
// 1D grid 1024 blocks, 128 thr = 2 waves. XCD pin: bh = (i&7)*8+((i>>3)&7).
// Wave wv owns q-tiles t = 2*(i>>6)+wv and 63-t (65 k-tile units each).
// Prefetch unclamped: overrun lands in adjacent d_ws regions (discarded).
// ---------------------------------------------------------------------------
__global__ __launch_bounds__(128, 2)
void attn_kernel(const __bf16* __restrict__ Q2, const __bf16* __restrict__ K2,
                 const __bf16* __restrict__ V2, __bf16* __restrict__ Yw)
{
    const int tid = threadIdx.x;
    const int lane = tid & 63;
    const int wv = tid >> 6;
    const int col = lane & 31;
    const int hi = lane >> 5;
    const int i0 = blockIdx.x;
    const int bh = (i0 & 7) * 8 + ((i0 >> 3) & 7);
    const int t = (i0 >> 6) * 2 + wv;          // 0..31
    const int tB = 63 - t;
    const int qA = t * 32;
    const int qB = tB * 32;
    const size_t tb = (size_t)bh * 64;         // tile base

    bf16x8 qfA[4], qfB[4];
#pragma unroll
    for (int dc = 0; dc < 4; ++dc) {
        qfA[dc] = *(const bf16x8*)&Q2[((tb + t) * 4 + dc) * 512 + lane * 8];
        qfB[dc] = *(const bf16x8*)&Q2[((tb + tB) * 4 + dc) * 512 + lane * 8];
    }

    bf16x8 ones;
#pragma unroll
    for (int j = 0; j < 8; ++j) ones[j] = (__bf16)1.0f;

    f32x16 CZ;
#pragma unroll
    for (int i = 0; i < 16; ++i) CZ[i] = 0.f;

    f32x16 OtA[2], OtB[2], OsA, OsB;
#pragma unroll
    for (int dt = 0; dt < 2; ++dt)
#pragma unroll
        for (int i = 0; i < 16; ++i) { OtA[dt][i] = 0.f; OtB[dt][i] = 0.f; }
#pragma unroll
    for (int i = 0; i < 16; ++i) { OsA[i] = 0.f; OsB[i] = 0.f; }

    // fixed-ref softmax + in-lane pack; l via ones-MFMA into Os.
    auto smxpack = [&](f32x16& st, f32x16& Os, bool diag,
                       bf16x8& pa0, bf16x8& pa1) {
        if (diag) {
#pragma unroll
            for (int r = 0; r < 16; ++r) {
                int crow = (r & 3) + 8 * (r >> 2) + 4 * hi;
                if (crow > col) st[r] = -1e30f;
            }
        }
#pragma unroll
        for (int r = 0; r < 16; ++r) st[r] = exp2f(st[r]);
        u32x4 w0 = {pkbf(st[0], st[1]), pkbf(st[2], st[3]),
                    pkbf(st[4], st[5]), pkbf(st[6], st[7])};
        u32x4 w1 = {pkbf(st[8], st[9]), pkbf(st[10], st[11]),
                    pkbf(st[12], st[13]), pkbf(st[14], st[15])};
        pa0 = __builtin_bit_cast(bf16x8, w0);
        pa1 = __builtin_bit_cast(bf16x8, w1);
        Os = MFMA32(ones, pa0, Os);
        Os = MFMA32(ones, pa1, Os);
    };

    const __bf16* kp = K2 + tb * 2048 + lane * 8;
    const __bf16* vp = V2 + tb * 2048 + lane * 8;

    // preload K(0), V(0)
    bf16x8 kfP[4], vfP[4];
#pragma unroll
    for (int dc = 0; dc < 4; ++dc) {
        kfP[dc] = *(const bf16x8*)&kp[dc * 512];
        vfP[dc] = *(const bf16x8*)&vp[dc * 512];
    }

    const int nsteps = tB + 1;
    for (int kt = 0; kt < nsteps; ++kt) {
        const bool dual = (kt <= t);

        f32x16 stA, stB;
        __builtin_amdgcn_s_setprio(1);
        stB = MFMA32(kfP[0], qfB[0], CZ);
        stB = MFMA32(kfP[1], qfB[1], stB);
        stB = MFMA32(kfP[2], qfB[2], stB);
        stB = MFMA32(kfP[3], qfB[3], stB);
        if (dual) {
            stA = MFMA32(kfP[0], qfA[0], CZ);
            stA = MFMA32(kfP[1], qfA[1], stA);
            stA = MFMA32(kfP[2], qfA[2], stA);
            stA = MFMA32(kfP[3], qfA[3], stA);
        }
        __builtin_amdgcn_s_setprio(0);

        // in-place K prefetch: kfP dead after QK^T issue; reload same regs.
        // Latency covered by 2x softmax + PV below. (Unclamped; overrun ok.)
        kp += 2048;
#pragma unroll
        for (int dc = 0; dc < 4; ++dc)
            kfP[dc] = *(const bf16x8*)&kp[dc * 512];

        bf16x8 paA0, paA1, paB0, paB1;
        smxpack(stB, OsB, kt == tB, paB0, paB1);
        if (dual) smxpack(stA, OsA, kt == t, paA0, paA1);

        __builtin_amdgcn_s_setprio(1);
        OtB[0] = MFMA32(vfP[0], paB0, OtB[0]);
        OtB[0] = MFMA32(vfP[1], paB1, OtB[0]);
        OtB[1] = MFMA32(vfP[2], paB0, OtB[1]);
        OtB[1] = MFMA32(vfP[3], paB1, OtB[1]);
        if (dual) {
            OtA[0] = MFMA32(vfP[0], paA0, OtA[0]);
            OtA[0] = MFMA32(vfP[1], paA1, OtA[0]);
            OtA[1] = MFMA32(vfP[2], paA0, OtA[1]);
            OtA[1] = MFMA32(vfP[3], paA1, OtA[1]);
        }
        __builtin_amdgcn_s_setprio(0);

        // in-place V prefetch: vfP dead after PV issue; reload same regs.
        // Latency covered by next step's QK^T + softmax.
        vp += 2048;
#pragma unroll
        for (int dc = 0; dc < 4; ++dc)
            vfP[dc] = *(const bf16x8*)&vp[dc * 512];
    }

    // ---- epilogue: O^T C-layout col=q(lane-local); l = Os[0] (rows equal)
    const int b = bh >> 4, h = bh & 15;
    const float invA = 1.f / OsA[0], invB = 1.f / OsB[0];
    __bf16* yrowA = Yw + ((size_t)(b * 2048 + qA + col)) * 1024 + h * 64;
    __bf16* yrowB = Yw + ((size_t)(b * 2048 + qB + col)) * 1024 + h * 64;
#pragma unroll
    for (int dt = 0; dt < 2; ++dt)
#pragma unroll
        for (int rg = 0; rg < 4; ++rg) {
            int d0 = dt * 32 + rg * 8 + hi * 4;
            unsigned lo = pkbf(OtA[dt][rg * 4 + 0] * invA, OtA[dt][rg * 4 + 1] * invA);
            unsigned h2 = pkbf(OtA[dt][rg * 4 + 2] * invA, OtA[dt][rg * 4 + 3] * invA);
            *(unsigned long long*)&yrowA[d0] =
                (unsigned long long)lo | ((unsigned long long)h2 << 32);
            lo = pkbf(OtB[dt][rg * 4 + 0] * invB, OtB[dt][rg * 4 + 1] * invB);
            h2 = pkbf(OtB[dt][rg * 4 + 2] * invB, OtB[dt][rg * 4 + 3] * invB);
            *(unsigned long long*)&yrowB[d0] =
                (unsigned long long)lo | ((unsigned long long)h2 << 32);
        }
}

// ---------------------------------------------------------------------------
extern "C" void kernel_launch(void* const* d_in, const int* in_sizes, int n_in,
                              void* d_out, int out_size, void* d_ws, size_t ws_size,
                              hipStream_t stream)
{
    const float* x     = (const float*)d_in[0];
    const float* wqkv  = (const float*)d_in[1];
    const float* bqkv  = (const float*)d_in[2];
    const float* wproj = (const float*)d_in[3];
    const float* bproj = (const float*)d_in[4];
    float* out = (float*)d_out;

    const size_t E = (size_t)4 * 16 * 2048 * 64;
    __bf16* q2     = (__bf16*)d_ws;               // E (pre-scaled, tiled)
    __bf16* k2     = q2 + E;                      // E (tiled)
    __bf16* v2     = k2 + E;                      // E (tiled, PV k-placement)
    __bf16* xb     = v2 + E;                      // E
    __bf16* y      = xb;                          // alias
    __bf16* wqkvT  = xb + E;
    __bf16* wprojT = wqkvT + (size_t)3072 * 1024;

    fused_convert_kernel<<<8192, 256, 0, stream>>>(x, xb, wqkv, wqkvT, wproj, wprojT);
    qkv_gemm_kernel<<<dim3(64, 24), 256, 0, stream>>>(xb, wqkvT, bqkv, q2, k2, v2);
    attn_kernel<<<1024, 128, 0, stream>>>(q2, k2, v2, y);
    proj_gemm_kernel<<<dim3(64, 8), 256, 0, stream>>>(y, wprojT, bproj, out);
}

// Round 23
// 151.357 us; speedup vs baseline: 1.7688x; 1.0035x over previous
//
#include <hip/hip_runtime.h>

// B=4, L=2048, D=1024, H=16, HD=64.
// d_in fp32: x, Wqkv, bqkv, Wproj, bproj. d_out fp32.
// Pipeline: ONE fused fp32->bf16 convert kernel; bf16 MFMA GEMMs with BK=64
// and DOUBLE-BUFFERED LDS + pipelined staging (STAGE next tile BEFORE
// computing current; ONE barrier per K-step -> the pre-barrier vmcnt drain
// overlaps compute); LDS-staged tiled epilogue; swapped-operand causal flash
// attention (unchanged from R22): dual-chain pair-balanced, shared K/V loads,
// in-place prefetch, lane-major tiled Q2/K2/V2, XCD bh-pin, fixed-reference
// softmax, lsum via ones-MFMA.
//
// Q2/K2 layout (bf16): addr(bh,l,hd) = ((bh*64 + (l>>5))*4 + (hd>>4))*512
//                                      + ((hd>>3)&1)*256 + (l&31)*8 + (hd&7)
// V2 layout (bf16):    addr(bh,l,hd) = ((bh*64 + (l>>5))*4 + (hd>>5)*2
//                                      + ((l>>4)&1))*512 + ((l>>2)&1)*256
//                                      + (hd&31)*8 + ((l&3)|(((l>>3)&1)<<2))

typedef __bf16 bf16x2 __attribute__((ext_vector_type(2)));
typedef __bf16 bf16x4 __attribute__((ext_vector_type(4)));
typedef __bf16 bf16x8 __attribute__((ext_vector_type(8)));
typedef float f32x4 __attribute__((ext_vector_type(4)));
typedef float f32x16 __attribute__((ext_vector_type(16)));
typedef unsigned u32x4 __attribute__((ext_vector_type(4)));

#define MFMA16(a, b, c) __builtin_amdgcn_mfma_f32_16x16x32_bf16(a, b, c, 0, 0, 0)
#define MFMA32(a, b, c) __builtin_amdgcn_mfma_f32_32x32x16_bf16(a, b, c, 0, 0, 0)

__device__ __forceinline__ void gload_lds16(const __bf16* g, __bf16* l) {
    __builtin_amdgcn_global_load_lds(
        (const __attribute__((address_space(1))) void*)g,
        (__attribute__((address_space(3))) void*)l, 16, 0, 0);
}

__device__ __forceinline__ unsigned pkbf(float a, float b) {
    bf16x2 t = {(__bf16)a, (__bf16)b};
    return __builtin_bit_cast(unsigned, t);
}

// ---------------------------------------------------------------------------
// Fused converts: blocks [0,4096) x->xb straight; [4096,7168) wqkv transpose;
// [7168,8192) wproj transpose. 256 threads each.
// ---------------------------------------------------------------------------
__global__ void fused_convert_kernel(const float* __restrict__ x, __bf16* __restrict__ xb,
                                     const float* __restrict__ wqkv, __bf16* __restrict__ wqkvT,
                                     const float* __restrict__ wproj, __bf16* __restrict__ wprojT)
{
    const int blk = blockIdx.x;
    if (blk < 4096) {
        int i = (blk * 256 + threadIdx.x) * 8;
        f32x4 lo = *(const f32x4*)&x[i];
        f32x4 hi = *(const f32x4*)&x[i + 4];
        bf16x8 o;
#pragma unroll
        for (int j = 0; j < 4; ++j) { o[j] = (__bf16)lo[j]; o[j + 4] = (__bf16)hi[j]; }
        *(bf16x8*)&xb[i] = o;
        return;
    }
    __shared__ __bf16 t[32][33];
    const float* in;
    __bf16* out;
    int R, C, bx, by;
    if (blk < 7168) {
        int b2 = blk - 4096;                 // wqkv: grid 96 x 32
        bx = b2 % 96; by = b2 / 96; in = wqkv; out = wqkvT; R = 1024; C = 3072;
    } else {
        int b2 = blk - 7168;                 // wproj: grid 32 x 32
        bx = b2 % 32; by = b2 / 32; in = wproj; out = wprojT; R = 1024; C = 1024;
    }
    const int c0 = bx * 32, r0 = by * 32;
    const int tx = threadIdx.x & 31, ty = threadIdx.x >> 5;
#pragma unroll
    for (int j = 0; j < 4; ++j) {
        int r = ty + j * 8;
        t[tx][r] = (__bf16)in[(size_t)(r0 + r) * C + c0 + tx];
    }
    __syncthreads();
#pragma unroll
    for (int j = 0; j < 4; ++j) {
        int r = ty + j * 8;
        out[(size_t)(c0 + r) * R + r0 + tx] = t[r][tx];
    }
}

// ---------------------------------------------------------------------------
// Pipelined double-buffered GEMM core, BK=64, one barrier per K-step.
// STAGE(tile k+1) is issued BEFORE computing tile k; __syncthreads at the
// step end drains those loads (overlapped with the 32 MFMAs) and fences the
// buffer swap. Source chunk pre-swizzled c=(lane&7)^(r&7); frag read applies
// the same XOR (involution) -> conflict-free ds_read_b128.
// ---------------------------------------------------------------------------
#define GEMM_STAGE(Abase, Bbase, Adst, Bdst, k0s)                                  \
    _Pragma("unroll")                                                              \
    for (int l = 0; l < 4; ++l) {                                                  \
        int base = l * 256 + w * 64;                                               \
        int r = (base >> 3) + (lane >> 3);                                         \
        int c = (lane & 7) ^ (r & 7);                                              \
        gload_lds16(&Abase[(size_t)(m0 + r) * 1024 + (k0s) + c * 8], &Adst[base * 8]); \
        gload_lds16(&Bbase[(size_t)(n0 + r) * 1024 + (k0s) + c * 8], &Bdst[base * 8]); \
    }

#define GEMM_COMPUTE(Asrc, Bsrc)                                                   \
    {                                                                              \
        bf16x8 af[2][4], bfr[2][4];                                                \
        _Pragma("unroll")                                                          \
        for (int kk = 0; kk < 2; ++kk) {                                           \
            _Pragma("unroll")                                                      \
            for (int mf = 0; mf < 4; ++mf) {                                       \
                int rr = wr * 64 + mf * 16 + row;                                  \
                af[kk][mf] = *(const bf16x8*)                                      \
                    &Asrc[rr * 64 + (((kk * 4 + g) ^ (rr & 7)) * 8)];              \
            }                                                                      \
            _Pragma("unroll")                                                      \
            for (int nf = 0; nf < 4; ++nf) {                                       \
                int rr = wc * 64 + nf * 16 + row;                                  \
                bfr[kk][nf] = *(const bf16x8*)                                     \
                    &Bsrc[rr * 64 + (((kk * 4 + g) ^ (rr & 7)) * 8)];              \
            }                                                                      \
        }                                                                          \
        __builtin_amdgcn_s_setprio(1);                                             \
        _Pragma("unroll")                                                          \
        for (int kk = 0; kk < 2; ++kk)                                             \
            _Pragma("unroll")                                                      \
            for (int mf = 0; mf < 4; ++mf)                                         \
                _Pragma("unroll")                                                  \
                for (int nf = 0; nf < 4; ++nf)                                     \
                    acc[mf][nf] = MFMA16(af[kk][mf], bfr[kk][nf], acc[mf][nf]);    \
        __builtin_amdgcn_s_setprio(0);                                             \
    }

#define GEMM_TILE_LOOP(Abase, Bbase)                                               \
    GEMM_STAGE(Abase, Bbase, As0, Bs0, 0)                                          \
    __syncthreads();                                                               \
    for (int k2 = 0; k2 < 1024; k2 += 128) {                                       \
        GEMM_STAGE(Abase, Bbase, As1, Bs1, k2 + 64)                                \
        GEMM_COMPUTE(As0, Bs0)                                                     \
        __syncthreads();                                                           \
        if (k2 + 128 < 1024) {                                                     \
            GEMM_STAGE(Abase, Bbase, As0, Bs0, k2 + 128)                           \
        }                                                                          \
        GEMM_COMPUTE(As1, Bs1)                                                     \
        __syncthreads();                                                           \
    }

// QKV GEMM. LDS-staged epilogue -> coalesced 1KB chunk stores into Q2/K2/V2.
__global__ __launch_bounds__(256, 2)
void qkv_gemm_kernel(const __bf16* __restrict__ A, const __bf16* __restrict__ Bt,
                     const float* __restrict__ bias,
                     __bf16* __restrict__ q2, __bf16* __restrict__ k2,
                     __bf16* __restrict__ v2)
{
    __shared__ __bf16 stage[32768];           // 64 KB: 2 x (As 16KB + Bs 16KB)
    __bf16* const As0 = stage;
    __bf16* const Bs0 = stage + 8192;
    __bf16* const As1 = stage + 16384;
    __bf16* const Bs1 = stage + 24576;
    const int tid = threadIdx.x;
    const int lane = tid & 63;
    const int w = tid >> 6;
    const int wr = w >> 1, wc = w & 1;
    const int row = lane & 15, g = lane >> 4;
    const int m0 = blockIdx.x * 128;
    const int n0 = blockIdx.y * 128;

    const f32x4 fzero = {0.f, 0.f, 0.f, 0.f};
    f32x4 acc[4][4];
#pragma unroll
    for (int a = 0; a < 4; ++a)
#pragma unroll
        for (int b = 0; b < 4; ++b) acc[a][b] = fzero;

    GEMM_TILE_LOOP(A, Bt)

    // last barrier already passed; each wave writes/reads only its own region
    const int part = n0 >> 10;                // 0=q 1=k 2=v (uniform per block)
    const float QSCL = 0.18033688f;           // 0.125 * log2(e)
    if (part == 2) {
#pragma unroll
        for (int mf = 0; mf < 4; ++mf)
#pragma unroll
            for (int nf = 0; nf < 4; ++nf) {
                int nl = nf * 16 + row;
                float bv = bias[n0 + wc * 64 + nl];
                bf16x4 pv;
#pragma unroll
                for (int i = 0; i < 4; ++i)
                    pv[i] = (__bf16)(acc[mf][nf][i] + bv);
                int c = (mf >> 1) * 4 + (nl >> 5) * 2 + (mf & 1);
                int off0 = (g & 1) * 256 + (nl & 31) * 8 + ((g >> 1) & 1) * 4;
                *(unsigned long long*)&stage[w * 4096 + c * 512 + off0] =
                    __builtin_bit_cast(unsigned long long, pv);
            }
    } else {
#pragma unroll
        for (int mf = 0; mf < 4; ++mf)
#pragma unroll
            for (int nf = 0; nf < 4; ++nf) {
                int nl = nf * 16 + row;
                float bv = bias[n0 + wc * 64 + nl];
#pragma unroll
                for (int i = 0; i < 4; ++i) {
                    int ml = mf * 16 + g * 4 + i;
                    float fv = acc[mf][nf][i] + bv;
                    if (part == 0) fv *= QSCL;
                    int c = (ml >> 5) * 4 + (nl >> 4);
                    int off = ((nl >> 3) & 1) * 256 + (ml & 31) * 8 + (nl & 7);
                    stage[w * 4096 + c * 512 + off] = (__bf16)fv;
                }
            }
    }
    {
        const int b = m0 >> 11;
        const int lbase5 = (m0 & 2047) >> 5;
        const int hh = ((n0 & 1023) >> 6) + wc;
        const size_t bh64 = (size_t)(b * 16 + hh) * 64;
        __bf16* dst = part == 0 ? q2 : (part == 1 ? k2 : v2);
#pragma unroll
        for (int c = 0; c < 8; ++c) {
            bf16x8 val = *(const bf16x8*)&stage[w * 4096 + c * 512 + lane * 8];
            size_t gbase = ((bh64 + lbase5 + wr * 2 + (c >> 2)) * 4 + (c & 3)) * 512;
            *(bf16x8*)&dst[gbase + lane * 8] = val;
        }
    }
}

__global__ __launch_bounds__(256, 2)
void proj_gemm_kernel(const __bf16* __restrict__ A, const __bf16* __restrict__ Bt,
                      const float* __restrict__ bias, float* __restrict__ out)
{
    __shared__ __bf16 stage[32768];           // 64 KB double-buffer
    __bf16* const As0 = stage;
    __bf16* const Bs0 = stage + 8192;
    __bf16* const As1 = stage + 16384;
    __bf16* const Bs1 = stage + 24576;
    const int tid = threadIdx.x;
    const int lane = tid & 63;
    const int w = tid >> 6;
    const int wr = w >> 1, wc = w & 1;
    const int row = lane & 15, g = lane >> 4;
    const int m0 = blockIdx.x * 128;
    const int n0 = blockIdx.y * 128;

    const f32x4 fzero = {0.f, 0.f, 0.f, 0.f};
    f32x4 acc[4][4];
#pragma unroll
    for (int a = 0; a < 4; ++a)
#pragma unroll
        for (int b = 0; b < 4; ++b) acc[a][b] = fzero;

    GEMM_TILE_LOOP(A, Bt)

#pragma unroll
    for (int mf = 0; mf < 4; ++mf)
#pragma unroll
        for (int nf = 0; nf < 4; ++nf) {
            int n = n0 + wc * 64 + nf * 16 + row;
            float bv = bias[n];
#pragma unroll
            for (int i = 0; i < 4; ++i) {
                int mm = m0 + wr * 64 + mf * 16 + g * 4 + i;
                out[(size_t)mm * 1024 + n] = acc[mf][nf][i] + bv;
            }
        }
}

// ---------------------------------------------------------------------------
// DUAL-CHAIN pair-balanced swapped-operand causal flash attention (KVBLK=32)
// with fixed-reference softmax and IN-PLACE K/V prefetch (unchanged R22).
// 1D grid 1024 blocks, 128 thr = 2 waves. XCD pin: bh = (i&7)*8+((i>>3)&7).
// Wave wv owns q-tiles t = 2*(i>>6)+wv and 63-t (65 k-tile units each).
// ---------------------------------------------------------------------------
__global__ __launch_bounds__(128, 2)
void attn_kernel(const __bf16* __restrict__ Q2, const __bf16* __restrict__ K2,
                 const __bf16* __restrict__ V2, __bf16* __restrict__ Yw)
{
    const int tid = threadIdx.x;
    const int lane = tid & 63;
    const int wv = tid >> 6;
    const int col = lane & 31;
    const int hi = lane >> 5;
    const int i0 = blockIdx.x;
    const int bh = (i0 & 7) * 8 + ((i0 >> 3) & 7);
    const int t = (i0 >> 6) * 2 + wv;          // 0..31
    const int tB = 63 - t;
    const int qA = t * 32;
    const int qB = tB * 32;
    const size_t tb = (size_t)bh * 64;         // tile base

    bf16x8 qfA[4], qfB[4];
#pragma unroll
    for (int dc = 0; dc < 4; ++dc) {
        qfA[dc] = *(const bf16x8*)&Q2[((tb + t) * 4 + dc) * 512 + lane * 8];
        qfB[dc] = *(const bf16x8*)&Q2[((tb + tB) * 4 + dc) * 512 + lane * 8];
    }

    bf16x8 ones;
#pragma unroll
    for (int j = 0; j < 8; ++j) ones[j] = (__bf16)1.0f;

    f32x16 CZ;
#pragma unroll
    for (int i = 0; i < 16; ++i) CZ[i] = 0.f;

    f32x16 OtA[2], OtB[2], OsA, OsB;
#pragma unroll
    for (int dt = 0; dt < 2; ++dt)
#pragma unroll
        for (int i = 0; i < 16; ++i) { OtA[dt][i] = 0.f; OtB[dt][i] = 0.f; }
#pragma unroll
    for (int i = 0; i < 16; ++i) { OsA[i] = 0.f; OsB[i] = 0.f; }

    auto smxpack = [&](f32x16& st, f32x16& Os, bool diag,
                       bf16x8& pa0, bf16x8& pa1) {
        if (diag) {
#pragma unroll
            for (int r = 0; r < 16; ++r) {
                int crow = (r & 3) + 8 * (r >> 2) + 4 * hi;
                if (crow > col) st[r] = -1e30f;
            }
        }
#pragma unroll
        for (int r = 0; r < 16; ++r) st[r] = exp2f(st[r]);
        u32x4 w0 = {pkbf(st[0], st[1]), pkbf(st[2], st[3]),
                    pkbf(st[4], st[5]), pkbf(st[6], st[7])};
        u32x4 w1 = {pkbf(st[8], st[9]), pkbf(st[10], st[11]),
                    pkbf(st[12], st[13]), pkbf(st[14], st[15])};
        pa0 = __builtin_bit_cast(bf16x8, w0);
        pa1 = __builtin_bit_cast(bf16x8, w1);
        Os = MFMA32(ones, pa0, Os);
        Os = MFMA32(ones, pa1, Os);
    };

    const __bf16* kp = K2 + tb * 2048 + lane * 8;
    const __bf16* vp = V2 + tb * 2048 + lane * 8;

    bf16x8 kfP[4], vfP[4];
#pragma unroll
    for (int dc = 0; dc < 4; ++dc) {
        kfP[dc] = *(const bf16x8*)&kp[dc * 512];
        vfP[dc] = *(const bf16x8*)&vp[dc * 512];
    }

    const int nsteps = tB + 1;
    for (int kt = 0; kt < nsteps; ++kt) {
        const bool dual = (kt <= t);

        f32x16 stA, stB;
        __builtin_amdgcn_s_setprio(1);
        stB = MFMA32(kfP[0], qfB[0], CZ);
        stB = MFMA32(kfP[1], qfB[1], stB);
        stB = MFMA32(kfP[2], qfB[2], stB);
        stB = MFMA32(kfP[3], qfB[3], stB);
        if (dual) {
            stA = MFMA32(kfP[0], qfA[0], CZ);
            stA = MFMA32(kfP[1], qfA[1], stA);
            stA = MFMA32(kfP[2], qfA[2], stA);
            stA = MFMA32(kfP[3], qfA[3], stA);
        }
        __builtin_amdgcn_s_setprio(0);

        // in-place K prefetch: kfP dead after QK^T issue; reload same regs.
        kp += 2048;
#pragma unroll
        for (int dc = 0; dc < 4; ++dc)
            kfP[dc] = *(const bf16x8*)&kp[dc * 512];

        bf16x8 paA0, paA1, paB0, paB1;
        smxpack(stB, OsB, kt == tB, paB0, paB1);
        if (dual) smxpack(stA, OsA, kt == t, paA0, paA1);

        __builtin_amdgcn_s_setprio(1);
        OtB[0] = MFMA32(vfP[0], paB0, OtB[0]);
        OtB[0] = MFMA32(vfP[1], paB1, OtB[0]);
        OtB[1] = MFMA32(vfP[2], paB0, OtB[1]);
        OtB[1] = MFMA32(vfP[3], paB1, OtB[1]);
        if (dual) {
            OtA[0] = MFMA32(vfP[0], paA0, OtA[0]);
            OtA[0] = MFMA32(vfP[1], paA1, OtA[0]);
            OtA[1] = MFMA32(vfP[2], paA0, OtA[1]);
            OtA[1] = MFMA32(vfP[3], paA1, OtA[1]);
        }
        __builtin_amdgcn_s_setprio(0);

        // in-place V prefetch: vfP dead after PV issue; reload same regs.
        vp += 2048;
#pragma unroll
        for (int dc = 0; dc < 4; ++dc)
            vfP[dc] = *(const bf16x8*)&vp[dc * 512];
    }

    const int b = bh >> 4, h = bh & 15;
    const float invA = 1.f / OsA[0], invB = 1.f / OsB[0];
    __bf16* yrowA = Yw + ((size_t)(b * 2048 + qA + col)) * 1024 + h * 64;
    __bf16* yrowB = Yw + ((size_t)(b * 2048 + qB + col)) * 1024 + h * 64;
#pragma unroll
    for (int dt = 0; dt < 2; ++dt)
#pragma unroll
        for (int rg = 0; rg < 4; ++rg) {
            int d0 = dt * 32 + rg * 8 + hi * 4;
            unsigned lo = pkbf(OtA[dt][rg * 4 + 0] * invA, OtA[dt][rg * 4 + 1] * invA);
            unsigned h2 = pkbf(OtA[dt][rg * 4 + 2] * invA, OtA[dt][rg * 4 + 3] * invA);
            *(unsigned long long*)&yrowA[d0] =
                (unsigned long long)lo | ((unsigned long long)h2 << 32);
            lo = pkbf(OtB[dt][rg * 4 + 0] * invB, OtB[dt][rg * 4 + 1] * invB);
            h2 = pkbf(OtB[dt][rg * 4 + 2] * invB, OtB[dt][rg * 4 + 3] * invB);
            *(unsigned long long*)&yrowB[d0] =
                (unsigned long long)lo | ((unsigned long long)h2 << 32);
        }
}

// ---------------------------------------------------------------------------
extern "C" void kernel_launch(void* const* d_in, const int* in_sizes, int n_in,
                              void* d_out, int out_size, void* d_ws, size_t ws_size,
                              hipStream_t stream)
{
    const float* x     = (const float*)d_in[0];
    const float* wqkv  = (const float*)d_in[1];
    const float* bqkv  = (const float*)d_in[2];
    const float* wproj = (const float*)d_in[3];
    const float* bproj = (const float*)d_in[4];
    float* out = (float*)d_out;

    const size_t E = (size_t)4 * 16 * 2048 * 64;
    __bf16* q2     = (__bf16*)d_ws;               // E (pre-scaled, tiled)
    __bf16* k2     = q2 + E;                      // E (tiled)
    __bf16* v2     = k2 + E;                      // E (tiled, PV k-placement)
    __bf16* xb     = v2 + E;                      // E
    __bf16* y      = xb;                          // alias
    __bf16* wqkvT  = xb + E;
    __bf16* wprojT = wqkvT + (size_t)3072 * 1024;

    fused_convert_kernel<<<8192, 256, 0, stream>>>(x, xb, wqkv, wqkvT, wproj, wprojT);
    qkv_gemm_kernel<<<dim3(64, 24), 256, 0, stream>>>(xb, wqkvT, bqkv, q2, k2, v2);
    attn_kernel<<<1024, 128, 0, stream>>>(q2, k2, v2, y);
    proj_gemm_kernel<<<dim3(64, 8), 256, 0, stream>>>(y, wprojT, bproj, out);
}